// Round 7
// baseline (286.045 us; speedup 1.0000x reference)
//
#include <hip/hip_runtime.h>
#include <math.h>

#define NQ 4
#define NL 2

// ---- LDS float-offset map (all float4-read regions 16B aligned) ----
#define O_XI   0                    // image x: 128 rows x stride 49 (pad -> banks 17*l, conflict-free)
#define O_XT   6272                 // text x: 128 rows x stride 17
#define O_WI1  8448                 // iW1 48x64 row-major [k][n]
#define O_WI2  11520                // iW2 64x4  [n][o]
#define O_WT1  11776                // tW1 16x32 [k][n]
#define O_WT2  12288                // tW2 32x4  [n][o]
#define O_IB1  12416                // ib1 64
#define O_TB1  12480                // tb1 32
#define O_FB2  12512                // ib2+tb2 fused, 4
#define O_CW1  12516                // 16
#define O_CB1  12532                // 16
#define O_CW2  12548                // 32
#define O_CB2  12580                // 2 (+2 pad)
#define O_PT   12584                // partial feats: 8 groups x 128 samples x stride 5
#define O_AS   17704                // A 16x16
#define O_MRE  17960                // circuit scratch
#define O_MIM  18216
#define LDS_FLOATS 18472            // 73,888 B -> 2 blocks/CU

// R7: register-tiled GEMM. Thread = 4 samples x 8 neurons (image) so one
// ds_read_b128 weight broadcast feeds 16 fma, one per-lane x read feeds 8.
// All hot-loop operands from LDS at short deterministic latency; no s_loads
// in the K-loop. Full unroll -> LDS immediate offsets, no addr math.
__global__ __launch_bounds__(256, 2) void qnn_fused(
    const float* __restrict__ text, const float* __restrict__ image,
    const float* __restrict__ tW1, const float* __restrict__ tb1,
    const float* __restrict__ tW2, const float* __restrict__ tb2,
    const float* __restrict__ iW1, const float* __restrict__ ib1,
    const float* __restrict__ iW2, const float* __restrict__ ib2,
    const float* __restrict__ qw,
    const float* __restrict__ cW1, const float* __restrict__ cb1,
    const float* __restrict__ cW2, const float* __restrict__ cb2,
    float* __restrict__ out, int B)
{
    __shared__ __align__(16) float S[LDS_FLOATS];
    const int tid = threadIdx.x;
    const int blk = blockIdx.x;

    // ================= staging (coalesced global reads) =================
    {   // image: 128 rows x 12 float4 = 1536 chunks, 6 per thread
        const float4* img4 = (const float4*)image;
        #pragma unroll
        for (int i = 0; i < 6; ++i) {
            int flat = i * 256 + tid;            // = sl*12 + c4
            int sl = flat / 12;
            int c4 = flat - sl * 12;
            int sg = blk * 128 + sl; if (sg >= B) sg = B - 1;
            float4 v = img4[(size_t)sg * 12 + c4];
            float* d = &S[O_XI + sl * 49 + c4 * 4];
            d[0] = v.x; d[1] = v.y; d[2] = v.z; d[3] = v.w;
        }
        // text: 128 rows x 4 float4 = 512 chunks, 2 per thread
        const float4* txt4 = (const float4*)text;
        #pragma unroll
        for (int i = 0; i < 2; ++i) {
            int flat = i * 256 + tid;            // = sl*4 + c4
            int sl = flat >> 2;
            int c4 = flat & 3;
            int sg = blk * 128 + sl; if (sg >= B) sg = B - 1;
            float4 v = txt4[(size_t)sg * 4 + c4];
            float* d = &S[O_XT + sl * 17 + c4 * 4];
            d[0] = v.x; d[1] = v.y; d[2] = v.z; d[3] = v.w;
        }
        #pragma unroll
        for (int i = 0; i < 12; ++i) S[O_WI1 + i*256 + tid] = iW1[i*256 + tid];
        S[O_WI2 + tid] = iW2[tid];
        #pragma unroll
        for (int i = 0; i < 2; ++i) S[O_WT1 + i*256 + tid] = tW1[i*256 + tid];
        if (tid < 128) S[O_WT2 + tid] = tW2[tid];
        if (tid < 64)  S[O_IB1 + tid] = ib1[tid];
        if (tid < 32)  S[O_TB1 + tid] = tb1[tid];
        if (tid < 4)   S[O_FB2 + tid] = ib2[tid] + tb2[tid];
        if (tid < 16) { S[O_CW1 + tid] = cW1[tid]; S[O_CB1 + tid] = cb1[tid]; }
        if (tid < 32)  S[O_CW2 + tid] = cW2[tid];
        if (tid < 2)   S[O_CB2 + tid] = cb2[tid];
    }

    // ---- circuit sim (threads 0-15; overlaps staging) ----
    if (tid < 16) {
        const int j = tid;
        float re[16], im[16];
        #pragma unroll
        for (int b = 0; b < 16; ++b) { re[b] = (b == j) ? 1.f : 0.f; im[b] = 0.f; }
        for (int l = 0; l < NL; ++l) {
            for (int i = 0; i < NQ; ++i) {
                float phi   = qw[(l*NQ + i)*3 + 0];
                float theta = qw[(l*NQ + i)*3 + 1];
                float omega = qw[(l*NQ + i)*3 + 2];
                float ct, st; __sincosf(0.5f*theta, &st, &ct);
                float cap, sap, cam, sam;
                __sincosf(0.5f*(phi + omega), &sap, &cap);
                __sincosf(0.5f*(phi - omega), &sam, &cam);
                float u00r =  cap*ct, u00i = -sap*ct;
                float u01r = -cam*st, u01i = -sam*st;
                float u10r =  cam*st, u10i = -sam*st;
                float u11r =  cap*ct, u11i =  sap*ct;
                int mask = 1 << (3 - i);
                #pragma unroll
                for (int b = 0; b < 16; ++b) {
                    if (b & mask) continue;
                    int b1 = b | mask;
                    float a0r = re[b],  a0i = im[b];
                    float a1r = re[b1], a1i = im[b1];
                    re[b]  = u00r*a0r - u00i*a0i + u01r*a1r - u01i*a1i;
                    im[b]  = u00r*a0i + u00i*a0r + u01r*a1i + u01i*a1r;
                    re[b1] = u10r*a0r - u10i*a0i + u11r*a1r - u11i*a1i;
                    im[b1] = u10r*a0i + u10i*a0r + u11r*a1i + u11i*a1r;
                }
            }
            #pragma unroll
            for (int b = 0; b < 16; ++b) {   // CZ chain masks 0xC,0x6,0x3
                float sgn = 1.f;
                if ((b & 0xC) == 0xC) sgn = -sgn;
                if ((b & 0x6) == 0x6) sgn = -sgn;
                if ((b & 0x3) == 0x3) sgn = -sgn;
                re[b] *= sgn; im[b] *= sgn;
            }
        }
        #pragma unroll
        for (int b = 0; b < 16; ++b) { S[O_MRE + j*16 + b] = re[b]; S[O_MIM + j*16 + b] = im[b]; }
    }
    __syncthreads();

    // ---- A[j][k] reduce (1 entry/thread); consumed in phase C after sync2
    {
        int j = tid >> 4, k = tid & 15;
        float sacc = 0.f;
        #pragma unroll
        for (int b = 0; b < 16; ++b) {
            float sg = (b & 8) ? -1.f : 1.f;
            sacc += sg * (S[O_MRE + j*16 + b]*S[O_MRE + k*16 + b] +
                          S[O_MIM + j*16 + b]*S[O_MIM + k*16 + b]);
        }
        S[O_AS + tid] = sacc;
    }

    // ================= tiled GEMMs =================
    const int lane = tid & 63;
    const int wave = tid >> 6;
    const int hw   = lane >> 5;          // half-wave selects octet
    const int l5   = lane & 31;          // sample sub-index; samples l5+32r

    float part[4][4];                    // [r][o] feats partials
    #pragma unroll
    for (int r = 0; r < 4; ++r)
        #pragma unroll
        for (int o = 0; o < 4; ++o) part[r][o] = 0.f;

    // ---- image layer: [48] -> relu[64]; this half-wave owns neurons nb..nb+7
    {
        const int nb = (wave*2 + hw) * 8;
        float acc[4][8];
        #pragma unroll
        for (int j = 0; j < 8; ++j) {
            float bv = S[O_IB1 + nb + j];
            acc[0][j] = bv; acc[1][j] = bv; acc[2][j] = bv; acc[3][j] = bv;
        }
        const float* x0p = &S[O_XI + (l5 +  0) * 49];
        const float* x1p = &S[O_XI + (l5 + 32) * 49];
        const float* x2p = &S[O_XI + (l5 + 64) * 49];
        const float* x3p = &S[O_XI + (l5 + 96) * 49];
        const float* wp  = &S[O_WI1 + nb];
        #pragma unroll
        for (int k = 0; k < 48; ++k) {
            float x0 = x0p[k], x1 = x1p[k], x2 = x2p[k], x3 = x3p[k];
            float4 wA = *(const float4*)&wp[k*64];
            float4 wB = *(const float4*)&wp[k*64 + 4];
            acc[0][0] = fmaf(x0, wA.x, acc[0][0]); acc[0][1] = fmaf(x0, wA.y, acc[0][1]);
            acc[0][2] = fmaf(x0, wA.z, acc[0][2]); acc[0][3] = fmaf(x0, wA.w, acc[0][3]);
            acc[0][4] = fmaf(x0, wB.x, acc[0][4]); acc[0][5] = fmaf(x0, wB.y, acc[0][5]);
            acc[0][6] = fmaf(x0, wB.z, acc[0][6]); acc[0][7] = fmaf(x0, wB.w, acc[0][7]);
            acc[1][0] = fmaf(x1, wA.x, acc[1][0]); acc[1][1] = fmaf(x1, wA.y, acc[1][1]);
            acc[1][2] = fmaf(x1, wA.z, acc[1][2]); acc[1][3] = fmaf(x1, wA.w, acc[1][3]);
            acc[1][4] = fmaf(x1, wB.x, acc[1][4]); acc[1][5] = fmaf(x1, wB.y, acc[1][5]);
            acc[1][6] = fmaf(x1, wB.z, acc[1][6]); acc[1][7] = fmaf(x1, wB.w, acc[1][7]);
            acc[2][0] = fmaf(x2, wA.x, acc[2][0]); acc[2][1] = fmaf(x2, wA.y, acc[2][1]);
            acc[2][2] = fmaf(x2, wA.z, acc[2][2]); acc[2][3] = fmaf(x2, wA.w, acc[2][3]);
            acc[2][4] = fmaf(x2, wB.x, acc[2][4]); acc[2][5] = fmaf(x2, wB.y, acc[2][5]);
            acc[2][6] = fmaf(x2, wB.z, acc[2][6]); acc[2][7] = fmaf(x2, wB.w, acc[2][7]);
            acc[3][0] = fmaf(x3, wA.x, acc[3][0]); acc[3][1] = fmaf(x3, wA.y, acc[3][1]);
            acc[3][2] = fmaf(x3, wA.z, acc[3][2]); acc[3][3] = fmaf(x3, wA.w, acc[3][3]);
            acc[3][4] = fmaf(x3, wB.x, acc[3][4]); acc[3][5] = fmaf(x3, wB.y, acc[3][5]);
            acc[3][6] = fmaf(x3, wB.z, acc[3][6]); acc[3][7] = fmaf(x3, wB.w, acc[3][7]);
        }
        // relu + second layer iW2 into feats partials
        #pragma unroll
        for (int j = 0; j < 8; ++j) {
            float4 w2 = *(const float4*)&S[O_WI2 + (nb + j) * 4];
            #pragma unroll
            for (int r = 0; r < 4; ++r) {
                float h = fmaxf(acc[r][j], 0.f);
                part[r][0] = fmaf(h, w2.x, part[r][0]);
                part[r][1] = fmaf(h, w2.y, part[r][1]);
                part[r][2] = fmaf(h, w2.z, part[r][2]);
                part[r][3] = fmaf(h, w2.w, part[r][3]);
            }
        }
    }

    // ---- text layer: [16] -> relu[32]; this half-wave owns neurons nbt..nbt+3
    {
        const int nbt = (wave*2 + hw) * 4;
        float acc[4][4];
        #pragma unroll
        for (int j = 0; j < 4; ++j) {
            float bv = S[O_TB1 + nbt + j];
            acc[0][j] = bv; acc[1][j] = bv; acc[2][j] = bv; acc[3][j] = bv;
        }
        const float* x0p = &S[O_XT + (l5 +  0) * 17];
        const float* x1p = &S[O_XT + (l5 + 32) * 17];
        const float* x2p = &S[O_XT + (l5 + 64) * 17];
        const float* x3p = &S[O_XT + (l5 + 96) * 17];
        const float* wp  = &S[O_WT1 + nbt];
        #pragma unroll
        for (int k = 0; k < 16; ++k) {
            float x0 = x0p[k], x1 = x1p[k], x2 = x2p[k], x3 = x3p[k];
            float4 w = *(const float4*)&wp[k*32];
            acc[0][0] = fmaf(x0, w.x, acc[0][0]); acc[0][1] = fmaf(x0, w.y, acc[0][1]);
            acc[0][2] = fmaf(x0, w.z, acc[0][2]); acc[0][3] = fmaf(x0, w.w, acc[0][3]);
            acc[1][0] = fmaf(x1, w.x, acc[1][0]); acc[1][1] = fmaf(x1, w.y, acc[1][1]);
            acc[1][2] = fmaf(x1, w.z, acc[1][2]); acc[1][3] = fmaf(x1, w.w, acc[1][3]);
            acc[2][0] = fmaf(x2, w.x, acc[2][0]); acc[2][1] = fmaf(x2, w.y, acc[2][1]);
            acc[2][2] = fmaf(x2, w.z, acc[2][2]); acc[2][3] = fmaf(x2, w.w, acc[2][3]);
            acc[3][0] = fmaf(x3, w.x, acc[3][0]); acc[3][1] = fmaf(x3, w.y, acc[3][1]);
            acc[3][2] = fmaf(x3, w.z, acc[3][2]); acc[3][3] = fmaf(x3, w.w, acc[3][3]);
        }
        #pragma unroll
        for (int j = 0; j < 4; ++j) {
            float4 w2 = *(const float4*)&S[O_WT2 + (nbt + j) * 4];
            #pragma unroll
            for (int r = 0; r < 4; ++r) {
                float h = fmaxf(acc[r][j], 0.f);
                part[r][0] = fmaf(h, w2.x, part[r][0]);
                part[r][1] = fmaf(h, w2.y, part[r][1]);
                part[r][2] = fmaf(h, w2.z, part[r][2]);
                part[r][3] = fmaf(h, w2.w, part[r][3]);
            }
        }
    }

    // ---- write partials: group g = wave*2+hw; sample stride 5 (pad)
    {
        const int g = wave*2 + hw;
        #pragma unroll
        for (int r = 0; r < 4; ++r) {
            float* d = &S[O_PT + g*640 + (l5 + 32*r)*5];
            d[0] = part[r][0]; d[1] = part[r][1]; d[2] = part[r][2]; d[3] = part[r][3];
        }
    }
    __syncthreads();

    // ================= phase C: per-sample epilogue (threads 0-127) =======
    if (tid < 128) {
        const int s = tid;
        float f0 = S[O_FB2+0], f1 = S[O_FB2+1], f2 = S[O_FB2+2], f3 = S[O_FB2+3];
        #pragma unroll
        for (int g = 0; g < 8; ++g) {
            const float* p = &S[O_PT + g*640 + s*5];
            f0 += p[0]; f1 += p[1]; f2 += p[2]; f3 += p[3];
        }
        // angles = feats*0.5*0.5
        float c0,s0v,c1,s1v,c2,s2v,c3,s3v;
        __sincosf(f0 * 0.25f, &s0v, &c0);
        __sincosf(f1 * 0.25f, &s1v, &c1);
        __sincosf(f2 * 0.25f, &s2v, &c2);
        __sincosf(f3 * 0.25f, &s3v, &c3);
        float p01[4] = { c0*c1, c0*s1v, s0v*c1, s0v*s1v };
        float p23[4] = { c2*c3, c2*s3v, s2v*c3, s2v*s3v };
        float psi[16];
        #pragma unroll
        for (int x = 0; x < 4; ++x)
            #pragma unroll
            for (int y = 0; y < 4; ++y)
                psi[x*4+y] = p01[x] * p23[y];

        float q = 0.f;
        #pragma unroll
        for (int j = 0; j < 16; ++j) {
            float row = 0.f;
            #pragma unroll
            for (int k4 = 0; k4 < 4; ++k4) {
                float4 a = *(const float4*)&S[O_AS + j*16 + k4*4];
                row = fmaf(a.x, psi[k4*4+0], row);
                row = fmaf(a.y, psi[k4*4+1], row);
                row = fmaf(a.z, psi[k4*4+2], row);
                row = fmaf(a.w, psi[k4*4+3], row);
            }
            q = fmaf(psi[j], row, q);
        }

        float o0 = S[O_CB2+0], o1 = S[O_CB2+1];
        #pragma unroll
        for (int j = 0; j < 16; ++j) {
            float h = fmaxf(fmaf(q, S[O_CW1+j], S[O_CB1+j]), 0.f);
            o0 = fmaf(h, S[O_CW2 + j*2 + 0], o0);
            o1 = fmaf(h, S[O_CW2 + j*2 + 1], o1);
        }
        int sg = blk * 128 + s;
        if (sg < B) ((float2*)out)[sg] = make_float2(o0, o1);
    }
}

extern "C" void kernel_launch(void* const* d_in, const int* in_sizes, int n_in,
                              void* d_out, int out_size, void* d_ws, size_t ws_size,
                              hipStream_t stream)
{
    const float* text  = (const float*)d_in[0];
    const float* image = (const float*)d_in[1];
    const float* tW1   = (const float*)d_in[2];
    const float* tb1   = (const float*)d_in[3];
    const float* tW2   = (const float*)d_in[4];
    const float* tb2   = (const float*)d_in[5];
    const float* iW1   = (const float*)d_in[6];
    const float* ib1   = (const float*)d_in[7];
    const float* iW2   = (const float*)d_in[8];
    const float* ib2   = (const float*)d_in[9];
    const float* qw    = (const float*)d_in[10];
    const float* cW1   = (const float*)d_in[11];
    const float* cb1   = (const float*)d_in[12];
    const float* cW2   = (const float*)d_in[13];
    const float* cb2   = (const float*)d_in[14];

    int B = in_sizes[0] / 16;
    int grid = (B + 127) / 128;   // 128 samples per 256-thread block

    qnn_fused<<<grid, 256, 0, stream>>>(
        text, image, tW1, tb1, tW2, tb2, iW1, ib1, iW2, ib2,
        qw, cW1, cb1, cW2, cb2, (float*)d_out, B);
}